// Round 2
// baseline (653.633 us; speedup 1.0000x reference)
//
#include <hip/hip_runtime.h>
#include <cstddef>

#define T_STEPS 205
#define BATCH   2048
#define NIN     33
#define NRNN    256
#define NKT     9           // K tiles of 32 covering k=0..287 (k=288 via rank-1 epilogue)
#define BB      8           // batch rows per block
#define NTHREADS 256        // 4 waves, 1 wave/SIMD
#define NTW     4           // n-tiles (16 cols) per wave

#define A_STRIDE  296       // fp16 elems per A row: >=289, mult of 8 (16B align)
#define WS_STRIDE 40        // fp16 elems per W-stage row: 32 + pad, mult of 8

typedef _Float16 half8 __attribute__((ext_vector_type(8)));
typedef float    f32x4 __attribute__((ext_vector_type(4)));
typedef unsigned int uintx2 __attribute__((ext_vector_type(2)));

// Barrier that waits ONLY on LDS ops (lgkmcnt), not global stores/loads.
__device__ __forceinline__ void lds_barrier() {
    asm volatile("s_waitcnt lgkmcnt(0)\n\ts_barrier" ::: "memory");
}

// Merge even/odd accumulator across lane halves:
// result = {a.lanes[0..31], b.lanes[0..31]}  (documented gfx950 builtin)
__device__ __forceinline__ float permlane_merge(float a, float b) {
    uintx2 r = __builtin_amdgcn_permlane32_swap(
        __builtin_bit_cast(unsigned int, a),
        __builtin_bit_cast(unsigned int, b), false, false);
    return __builtin_bit_cast(float, r[0]);
}

// Layout (unchanged from the proven kernel):
// A (LDS, fp16, double-buffered; rows 0..7 real, 8..15 stay zero):
//   k = 0..32   : x_t[b][0..32]
//   k = 33..287 : h[b][0..254]
//   slot 288    : h[b][255]   (rank-1 remainder, applied in epilogue via VALU)
//
// R2/R3 restructure: 4 waves (was 8) x NTW=4 (was 2).
//  - halves the redundant LDS A-frag traffic (A is wave-invariant: 36 vs 72
//    ds_read_b128/step) -> LDS pipe ~430 cyc < MFMA pipe ~700 cyc per step
//  - permlane32_swap epilogue: merge even/odd n-tile accs across lane halves
//    so ALL 64 lanes do epilogue work (2 cols x 4 rows each) -> wave-level
//    VALU/store/ds_write instruction count halves, q<2 divergence gone.

__global__ __launch_bounds__(NTHREADS, 1)
void leaky_rnn_kernel(const float* __restrict__ x,
                      const float* __restrict__ W,
                      const float* __restrict__ bias,
                      const float* __restrict__ h0,
                      float* __restrict__ out)
{
    __shared__ _Float16 A_lds[2][16 * A_STRIDE];
    __shared__ _Float16 Wst[NRNN * WS_STRIDE];

    const int tid  = threadIdx.x;
    const int lane = tid & 63;
    const int wave = tid >> 6;      // 0..3
    const int q    = lane >> 4;     // quad 0..3
    const int nlo  = lane & 15;
    const int qe   = q & 1;         // post-swap row group: rows qe*4 + r
    const int hi   = lane >> 5;     // 0: even n-tile of pair, 1: odd
    const int b0   = blockIdx.x * BB;

    // zero both A buffers (pad rows 8..15 must read as 0 forever)
    for (int i = tid; i < 2 * 16 * A_STRIDE; i += NTHREADS)
        (&A_lds[0][0])[i] = (_Float16)0.f;   // flat over both buffers

    // ---- one-time: stage W rows 0..287 (fp32->fp16), pull B-frags to regs ----
    half8 wfrag[NTW][NKT];
    {
        const int c = tid;               // 0..255: W column this thread packs
        #pragma unroll
        for (int kt = 0; kt < NKT; ++kt) {
            __syncthreads();             // init phase: full barrier is fine here
            #pragma unroll
            for (int o = 0; o < 4; ++o) {    // k-octet within the 32-row chunk
                half8 pack;
                #pragma unroll
                for (int i = 0; i < 8; ++i)
                    pack[i] = (_Float16)W[(kt * 32 + o * 8 + i) * NRNN + c]; // coalesced over c
                *(half8*)&Wst[c * WS_STRIDE + o * 8] = pack;  // [col][k] transposed
            }
            __syncthreads();
            #pragma unroll
            for (int nt = 0; nt < NTW; ++nt) {
                int n = (wave * NTW + nt) * 16 + nlo;
                // B-frag layout (16x16x32): n = lane&15, k = (lane>>4)*8 + i
                wfrag[nt][kt] = *(const half8*)&Wst[n * WS_STRIDE + q * 8];
            }
        }
    }

    // per-lane epilogue mapping (post-permlane layout): pair p2 in {0,1}
    int ecol[2]; int slot[2]; float bve[2]; float w288e[2];
    #pragma unroll
    for (int p2 = 0; p2 < 2; ++p2) {
        ecol[p2]  = wave * (NTW * 16) + (2 * p2 + hi) * 16 + nlo;
        slot[p2]  = (ecol[p2] == 255) ? 288 : (33 + ecol[p2]);
        bve[p2]   = bias[ecol[p2]];
        w288e[p2] = W[288 * NRNN + ecol[p2]];    // last K row, applied via VALU
    }

    // x staging map (t-invariant): 256 threads own elements 0..255;
    // threads 0..7 additionally own elements 256..263 (BB*NIN = 264)
    const int  xb    = tid / NIN;
    const int  xi    = tid - xb * NIN;
    const int  xoff  = (b0 + xb) * NIN + xi;
    const int  e2    = NTHREADS + tid;
    const int  xb2   = e2 / NIN;
    const int  xi2   = e2 - xb2 * NIN;
    const int  xoff2 = (b0 + xb2) * NIN + xi2;
    const bool xact2 = (tid < BB * NIN - NTHREADS);   // tid < 8

    // ---- initial state into buf 0: x[0] + h0; h also into registers ----
    float hreg[2][4];
    #pragma unroll
    for (int p2 = 0; p2 < 2; ++p2)
        #pragma unroll
        for (int r = 0; r < 4; ++r) {
            int b = qe * 4 + r;
            float h = h0[(b0 + b) * NRNN + ecol[p2]];
            hreg[p2][r] = h;
            A_lds[0][b * A_STRIDE + slot[p2]] = (_Float16)h;
        }
    A_lds[0][xb * A_STRIDE + xi] = (_Float16)x[xoff];
    if (xact2) A_lds[0][xb2 * A_STRIDE + xi2] = (_Float16)x[xoff2];
    __syncthreads();   // end of init: full barrier once

    const int am = nlo;   // A-frag row: m = lane&15
    int p = 0;
    for (int t = 0; t < T_STEPS; ++t) {
        // prefetch next x into registers (vmcnt waited only at the consumer)
        const int tn = (t + 1 < T_STEPS) ? (t + 1) : (T_STEPS - 1);
        float xv  = x[(size_t)tn * (BATCH * NIN) + xoff];
        float xv2 = 0.f;
        if (xact2) xv2 = x[(size_t)tn * (BATCH * NIN) + xoff2];

        f32x4 acc[NTW];
        #pragma unroll
        for (int nt = 0; nt < NTW; ++nt) acc[nt] = (f32x4){0.f, 0.f, 0.f, 0.f};

        const _Float16* __restrict__ Ar = A_lds[p];
        _Float16* __restrict__ Aw = A_lds[p ^ 1];

        #pragma unroll
        for (int kt = 0; kt < NKT; ++kt) {
            // A-frag: m = lane&15, k = kt*32 + (lane>>4)*8 + i -> one ds_read_b128
            half8 af = *(const half8*)&Ar[am * A_STRIDE + kt * 32 + q * 8];
            #pragma unroll
            for (int nt = 0; nt < NTW; ++nt)
                acc[nt] = __builtin_amdgcn_mfma_f32_16x16x32_f16(af, wfrag[nt][kt], acc[nt], 0, 0, 0);
        }

        // old h[b][255] from the read buffer (broadcast reads, conflict-free)
        float h255[4];
        #pragma unroll
        for (int r = 0; r < 4; ++r)
            h255[r] = (float)Ar[(qe * 4 + r) * A_STRIDE + 288];

        // merge accs across lane halves: lanes<32 keep even n-tile rows 0..7,
        // lanes>=32 receive odd n-tile rows 0..7. C layout row=(lane>>4)*4+reg,
        // col=lane&15: valid rows live in lanes 0..31 of each acc.
        float m[2][4];
        #pragma unroll
        for (int p2 = 0; p2 < 2; ++p2)
            #pragma unroll
            for (int r = 0; r < 4; ++r)
                m[p2][r] = permlane_merge(acc[2 * p2][r], acc[2 * p2 + 1][r]);

        // epilogue (ALL 64 lanes): h update; LDS writes first (critical for
        // next step), global out-stores after (fire-and-forget).
        float hn_[2][4];
        #pragma unroll
        for (int p2 = 0; p2 < 2; ++p2)
            #pragma unroll
            for (int r = 0; r < 4; ++r) {
                float pre = m[p2][r] + bve[p2] + h255[r] * w288e[p2];
                float hn  = 0.8f * hreg[p2][r] + 0.2f * fmaxf(pre, 0.f);
                hreg[p2][r] = hn;
                hn_[p2][r]  = hn;
                Aw[(qe * 4 + r) * A_STRIDE + slot[p2]] = (_Float16)hn;
            }
        Aw[xb * A_STRIDE + xi] = (_Float16)xv;
        if (xact2) Aw[xb2 * A_STRIDE + xi2] = (_Float16)xv2;

        float* op = out + (size_t)t * (BATCH * NRNN) + (size_t)(b0 + qe * 4) * NRNN;
        #pragma unroll
        for (int p2 = 0; p2 < 2; ++p2)
            #pragma unroll
            for (int r = 0; r < 4; ++r)
                op[(size_t)r * NRNN + ecol[p2]] = hn_[p2][r];

        lds_barrier();   // LDS-only wait: out-stores keep draining in background
        p ^= 1;
    }
}

extern "C" void kernel_launch(void* const* d_in, const int* in_sizes, int n_in,
                              void* d_out, int out_size, void* d_ws, size_t ws_size,
                              hipStream_t stream) {
    const float* x    = (const float*)d_in[0];
    const float* W    = (const float*)d_in[1];   // (289, 256) row-major
    const float* bias = (const float*)d_in[2];
    const float* h0   = (const float*)d_in[3];
    float* out = (float*)d_out;

    dim3 grid(BATCH / BB);      // 256 blocks -> 1 per CU
    dim3 block(NTHREADS);       // 4 waves
    leaky_rnn_kernel<<<grid, block, 0, stream>>>(x, W, bias, h0, out);
}

// Round 3
// 503.715 us; speedup vs baseline: 1.2976x; 1.2976x over previous
//
#include <hip/hip_runtime.h>
#include <cstddef>

#define T_STEPS 205
#define BATCH   2048
#define NIN     33
#define NRNN    256
#define BB      8           // batch rows per block
#define NTHREADS 512        // 8 waves, 2 per SIMD
#define NTW     2           // n-tiles (16 cols) per wave

// K layout (reorganized): k = 0..255 -> h[k] (W row 33+k), k = 256..287 ->
// x[k-256] (W rows 0..31), k = 288 -> x[32] (W row 32, rank-1 via VALU).
// h fills exactly 8 MFMA K-tiles; the x K-tile (kt=8) is read DIRECTLY from
// the per-t x LDS region. The t-loop contains ZERO global loads -> no vmcnt
// wait ever -> out-stores can never serialize the step (R2 post-mortem: the
// xv consumption waited, in vmcnt in-order retirement, on the previous
// step's 8 HBM stores -> invariant ~3500 cyc/step with all pipes idle).

#define A_STRIDE  264       // h row stride (fp16): 256 + 8 pad (bank offset 4)
#define X_BSTRIDE 40        // x row stride (fp16): 33 -> 40 (16B aligned)
#define X_TSTRIDE (BB * X_BSTRIDE)          // 320 fp16 per t
#define X_ELEMS   ((T_STEPS + 1) * X_TSTRIDE) // +1 pad row (am=8..15 overread)
#define WS_STRIDE 40        // fp16 elems per W-stage row

typedef _Float16 half8 __attribute__((ext_vector_type(8)));
typedef float    f32x4 __attribute__((ext_vector_type(4)));
typedef unsigned int uintx2 __attribute__((ext_vector_type(2)));

// Barrier that waits ONLY on LDS ops (lgkmcnt), never vmcnt.
__device__ __forceinline__ void lds_barrier() {
    asm volatile("s_waitcnt lgkmcnt(0)\n\ts_barrier" ::: "memory");
}

// result = {a.lanes[0..31], b.lanes[0..31]}
__device__ __forceinline__ float permlane_merge(float a, float b) {
    uintx2 r = __builtin_amdgcn_permlane32_swap(
        __builtin_bit_cast(unsigned int, a),
        __builtin_bit_cast(unsigned int, b), false, false);
    return __builtin_bit_cast(float, r[0]);
}

__device__ __forceinline__ int grow(int kk) {   // gemm-k -> W row
    return (kk < NRNN) ? (33 + kk) : (kk - NRNN);
}

__global__ __launch_bounds__(NTHREADS, 1)
void leaky_rnn_kernel(const float* __restrict__ x,
                      const float* __restrict__ W,
                      const float* __restrict__ bias,
                      const float* __restrict__ h0,
                      float* __restrict__ out)
{
    // A: h only, double-buffered, rows 0..7 real / 8..15 zero. 16.9 KB.
    // X:全 x slice fp16 [t][b][40], 129.4 KB (W-staging region aliases its head).
    __shared__ __align__(16) _Float16 A_lds[2][16 * A_STRIDE];
    __shared__ __align__(16) _Float16 X_lds[X_ELEMS];

    const int tid  = threadIdx.x;
    const int lane = tid & 63;
    const int wave = tid >> 6;      // 0..7
    const int q    = lane >> 4;     // quad 0..3
    const int nlo  = lane & 15;
    const int qe   = q & 1;         // post-merge row group: rows qe*4 + r
    const int hi   = lane >> 5;     // 0: even n-tile of pair, 1: odd
    const int b0   = blockIdx.x * BB;

    // zero A (both buffers; pad rows 8..15 must stay 0 forever) + X pad row
    for (int i = tid; i < 2 * 16 * A_STRIDE; i += NTHREADS)
        (&A_lds[0][0])[i] = (_Float16)0.f;
    for (int i = tid; i < X_TSTRIDE; i += NTHREADS)
        X_lds[T_STEPS * X_TSTRIDE + i] = (_Float16)0.f;

    // ---- one-time: stage W (permuted rows, fp32->fp16), pull B-frags ----
    _Float16* Wst = &X_lds[0];      // dead after init; x preload reuses it
    half8 wfrag[NTW][9];
    {
        const int c   = tid & 255;  // W column this thread packs
        const int oct = tid >> 8;   // 0..1
        #pragma unroll
        for (int kt = 0; kt < 9; ++kt) {
            __syncthreads();
            #pragma unroll
            for (int o2 = 0; o2 < 2; ++o2) {
                int o = oct + 2 * o2;       // k-octet 0..3 within 32-chunk
                half8 pack;
                #pragma unroll
                for (int i = 0; i < 8; ++i)
                    pack[i] = (_Float16)W[grow(kt * 32 + o * 8 + i) * NRNN + c];
                *(half8*)&Wst[c * WS_STRIDE + o * 8] = pack;
            }
            __syncthreads();
            #pragma unroll
            for (int nt = 0; nt < NTW; ++nt) {
                int n = wave * 32 + nt * 16 + nlo;
                wfrag[nt][kt] = *(const half8*)&Wst[n * WS_STRIDE + q * 8];
            }
        }
        __syncthreads();   // all frag reads done before x preload clobbers Wst
    }

    // per-lane epilogue constants (post-merge layout)
    const int   ecol = wave * 32 + hi * 16 + nlo;   // 0..255
    const float bve  = bias[ecol];
    const float w32e = W[32 * NRNN + ecol];         // rank-1 row (x[32])

    // ---- preload ALL x for this block: fp32 global -> fp16 LDS ----
    // block slice per t is 264 contiguous floats at x[(t*BATCH+b0)*33]
    #pragma unroll 2
    for (int e = tid; e < T_STEPS * (BB * NIN); e += NTHREADS) {
        int t  = e / (BB * NIN);
        int i  = e - t * (BB * NIN);
        int b  = i / NIN;
        int xi = i - b * NIN;
        float v = x[(size_t)t * (BATCH * NIN) + (size_t)b0 * NIN + i];
        X_lds[t * X_TSTRIDE + b * X_BSTRIDE + xi] = (_Float16)v;
    }

    // ---- h0 -> A buf0 + registers ----
    float hreg[4];
    #pragma unroll
    for (int r = 0; r < 4; ++r) {
        int b = qe * 4 + r;
        float h = h0[(b0 + b) * NRNN + ecol];
        hreg[r] = h;
        A_lds[0][b * A_STRIDE + ecol] = (_Float16)h;
    }
    __syncthreads();   // end of init

    const int am = nlo;   // A-frag row: m = lane&15
    int p = 0;
    for (int t = 0; t < T_STEPS; ++t) {
        const _Float16* __restrict__ Ar = A_lds[p];
        _Float16* __restrict__ Aw = A_lds[p ^ 1];
        const _Float16* __restrict__ Xt = &X_lds[t * X_TSTRIDE];

        // x K-tile frag + rank-1 x[32] values: issue early, latency hides
        half8 xf = *(const half8*)&Xt[am * X_BSTRIDE + q * 8];
        float x32v[4];
        #pragma unroll
        for (int r = 0; r < 4; ++r)
            x32v[r] = (float)Xt[(qe * 4 + r) * X_BSTRIDE + 32];

        // split-K accumulators: 4 independent MFMA chains per wave
        f32x4 acc[NTW][2];
        #pragma unroll
        for (int nt = 0; nt < NTW; ++nt)
            #pragma unroll
            for (int s = 0; s < 2; ++s) acc[nt][s] = (f32x4){0.f, 0.f, 0.f, 0.f};

        #pragma unroll
        for (int kt = 0; kt < 8; ++kt) {
            half8 af = *(const half8*)&Ar[am * A_STRIDE + kt * 32 + q * 8];
            acc[0][kt & 1] = __builtin_amdgcn_mfma_f32_16x16x32_f16(af, wfrag[0][kt], acc[0][kt & 1], 0, 0, 0);
            acc[1][kt & 1] = __builtin_amdgcn_mfma_f32_16x16x32_f16(af, wfrag[1][kt], acc[1][kt & 1], 0, 0, 0);
        }
        acc[0][0] = __builtin_amdgcn_mfma_f32_16x16x32_f16(xf, wfrag[0][8], acc[0][0], 0, 0, 0);
        acc[1][0] = __builtin_amdgcn_mfma_f32_16x16x32_f16(xf, wfrag[1][8], acc[1][0], 0, 0, 0);

        f32x4 s0 = acc[0][0] + acc[0][1];
        f32x4 s1 = acc[1][0] + acc[1][1];

        // merge n-tile pair across lane halves; epilogue on ALL 64 lanes.
        float hn_[4];
        #pragma unroll
        for (int r = 0; r < 4; ++r) {
            float m   = permlane_merge(s0[r], s1[r]);
            float pre = m + bve + x32v[r] * w32e;
            float hn  = 0.8f * hreg[r] + 0.2f * fmaxf(pre, 0.f);
            hreg[r] = hn;
            hn_[r]  = hn;
            Aw[(qe * 4 + r) * A_STRIDE + ecol] = (_Float16)hn;   // LDS first
        }
        float* op = out + ((size_t)t * BATCH + b0 + qe * 4) * NRNN + ecol;
        #pragma unroll
        for (int r = 0; r < 4; ++r)                               // then HBM
            __builtin_nontemporal_store(hn_[r], op + (size_t)r * NRNN);

        lds_barrier();   // lgkmcnt only; stores are never waited on
        p ^= 1;
    }
}

extern "C" void kernel_launch(void* const* d_in, const int* in_sizes, int n_in,
                              void* d_out, int out_size, void* d_ws, size_t ws_size,
                              hipStream_t stream) {
    const float* x    = (const float*)d_in[0];
    const float* W    = (const float*)d_in[1];   // (289, 256) row-major
    const float* bias = (const float*)d_in[2];
    const float* h0   = (const float*)d_in[3];
    float* out = (float*)d_out;

    dim3 grid(BATCH / BB);      // 256 blocks -> 1 per CU
    dim3 block(NTHREADS);       // 8 waves
    leaky_rnn_kernel<<<grid, block, 0, stream>>>(x, W, bias, h0, out);
}